// Round 12
// baseline (188.244 us; speedup 1.0000x reference)
//
#include <hip/hip_runtime.h>
#include <cstdint>

typedef unsigned short u16;
typedef __attribute__((ext_vector_type(8))) short short8;
typedef __attribute__((ext_vector_type(4))) short short4v;
typedef __attribute__((ext_vector_type(4))) float f32x4;

#define NTOK 2048
#define CDIM 1024
#define C3   3072
#define NH   8
#define HD   128

__device__ __forceinline__ float bf2f(u16 u) {
    return __uint_as_float(((unsigned)u) << 16);
}
__device__ __forceinline__ u16 f2bf(float f) {
    unsigned u = __float_as_uint(f);
    u += 0x7fffu + ((u >> 16) & 1u);
    return (u16)(u >> 16);
}
// async 16B global->LDS DMA; LDS dest must be wave-uniform base + lane*16
__device__ __forceinline__ void gld_lds16(const u16* g, u16* l) {
    __builtin_amdgcn_global_load_lds(
        (__attribute__((address_space(1))) void*)(u16*)g,
        (__attribute__((address_space(3))) void*)l, 16, 0, 0);
}

// ---------------------------------------------------------------- K0: f32->bf16
__global__ __launch_bounds__(256) void k_cast(const float* __restrict__ x,
                                              const float* __restrict__ w,
                                              u16* __restrict__ xb,
                                              u16* __restrict__ wb) {
    int t = blockIdx.x * blockDim.x + threadIdx.x;
    int stride = gridDim.x * blockDim.x;
    for (int i = t; i < (NTOK * CDIM) / 4; i += stride) {
        float4 v = ((const float4*)x)[i];
        ushort4 o;
        o.x = f2bf(v.x); o.y = f2bf(v.y); o.z = f2bf(v.z); o.w = f2bf(v.w);
        ((ushort4*)xb)[i] = o;
    }
    for (int i = t; i < (C3 * CDIM) / 4; i += stride) {
        float4 v = ((const float4*)w)[i];
        ushort4 o;
        o.x = f2bf(v.x); o.y = f2bf(v.y); o.z = f2bf(v.z); o.w = f2bf(v.w);
        ((ushort4*)wb)[i] = o;
    }
}

// ---------------------------------------------------------------- K1: fused QKV GEMM + norm/x_ori/Vt epilogue
// R13 VERSION (verified). Single-barrier double-buffered DMA K-loop.
// R14 NOTE: BM=64 balanced-grid rewrite FAILED (absmax 1.68, output 0);
// reverted. Do not retry without host-side unit test of the index mapping.
__global__ __launch_bounds__(256) void k_qkvn(const u16* __restrict__ A,
                                              const u16* __restrict__ B,
                                              u16* __restrict__ Qn,
                                              u16* __restrict__ Kn,
                                              u16* __restrict__ Vn,
                                              u16* __restrict__ Vt,
                                              float* __restrict__ out) {
    __shared__ u16 SB[2][16384];     // per buf: As = [0:8192], Bs = [8192:16384]
    __shared__ float rowssq[128][2];
    u16* T = (u16*)SB;               // epilogue reuse: T[128][136] (34.8 KB)
    const int tid = threadIdx.x;
    const int lane = tid & 63;
    const int wid = tid >> 6;
    const int wm = wid >> 1, wn = wid & 1;
    const int q = lane >> 4, l16 = lane & 15;
    const int s = blockIdx.x;            // head-slice 0..23
    const int which = s >> 3, h = s & 7; // 0=q 1=k 2=v
    const int m0 = blockIdx.y * 128, n0 = s * 128;

    const u16* aP[4];
    const u16* bP[4];
#pragma unroll
    for (int t = 0; t < 4; t++) {
        int sl = tid + t * 256;
        int r = sl >> 3, c = (sl & 7) * 8;
        aP[t] = &A[(long long)(m0 + r) * CDIM + c];
        bP[t] = &B[(long long)(n0 + r) * CDIM + c];
    }
    // prologue: tile 0 into buffer 0
#pragma unroll
    for (int t = 0; t < 4; t++) {
        int sl = tid + t * 256;
        gld_lds16(aP[t], &SB[0][sl * 8]);
        gld_lds16(bP[t], &SB[0][8192 + sl * 8]);
        aP[t] += 64;
        bP[t] += 64;
    }

    f32x4 zero4 = {0.f, 0.f, 0.f, 0.f};
    f32x4 acc[4][4];
#pragma unroll
    for (int i = 0; i < 4; i++)
#pragma unroll
        for (int j = 0; j < 4; j++) acc[i][j] = zero4;

    for (int jt = 0; jt < 16; ++jt) {
        const u16* As = SB[jt & 1];
        const u16* Bs = SB[jt & 1] + 8192;
        asm volatile("s_waitcnt vmcnt(0)" ::: "memory");  // own DMAs for buf[cur]
        __builtin_amdgcn_s_barrier();                     // all waves' DMAs landed
        asm volatile("" ::: "memory");
        if (jt < 15) {   // issue next tile into the other buffer NOW
            u16* Sx = SB[(jt + 1) & 1];
#pragma unroll
            for (int t = 0; t < 4; t++) {
                int sl = tid + t * 256;
                gld_lds16(aP[t], &Sx[sl * 8]);
                gld_lds16(bP[t], &Sx[8192 + sl * 8]);
                aP[t] += 64;
                bP[t] += 64;
            }
        }
#pragma unroll
        for (int ks = 0; ks < 2; ks++) {
            short8 af[4], bfr[4];
#pragma unroll
            for (int tm = 0; tm < 4; tm++)
                af[tm] = *(const short8*)&As[(wm * 64 + tm * 16 + l16) * 64 + ks * 32 + q * 8];
#pragma unroll
            for (int tn = 0; tn < 4; tn++)
                bfr[tn] = *(const short8*)&Bs[(wn * 64 + tn * 16 + l16) * 64 + ks * 32 + q * 8];
#pragma unroll
            for (int tm = 0; tm < 4; tm++)
#pragma unroll
                for (int tn = 0; tn < 4; tn++)
                    acc[tm][tn] = __builtin_amdgcn_mfma_f32_16x16x32_bf16(
                        af[tm], bfr[tn], acc[tm][tn], 0, 0, 0);
        }
    }

    __syncthreads();  // all LDS reads done; SB reusable as T, rowssq writable
    // per-row sum of squares: this wave's 64-col half, then cross-wave via LDS
#pragma unroll
    for (int tm = 0; tm < 4; tm++)
#pragma unroll
        for (int r = 0; r < 4; r++) {
            float p = 0.f;
#pragma unroll
            for (int tn = 0; tn < 4; tn++) p += acc[tm][tn][r] * acc[tm][tn][r];
            p += __shfl_xor(p, 1);
            p += __shfl_xor(p, 2);
            p += __shfl_xor(p, 4);
            p += __shfl_xor(p, 8);
            if (l16 == 0) rowssq[wm * 64 + tm * 16 + q * 4 + r][wn] = p;
        }
    __syncthreads();
    float rinv[4][4];
#pragma unroll
    for (int tm = 0; tm < 4; tm++)
#pragma unroll
        for (int r = 0; r < 4; r++) {
            int rl = wm * 64 + tm * 16 + q * 4 + r;
            rinv[tm][r] = rsqrtf(rowssq[rl][0] + rowssq[rl][1]);
        }
    // normalized bf16 store to Qn/Kn/Vn
    u16* dstBase = (which == 0 ? Qn : which == 1 ? Kn : Vn);
#pragma unroll
    for (int tm = 0; tm < 4; tm++)
#pragma unroll
        for (int tn = 0; tn < 4; tn++)
#pragma unroll
            for (int r = 0; r < 4; r++) {
                int rl = wm * 64 + tm * 16 + q * 4 + r;
                int d = wn * 64 + tn * 16 + l16;
                dstBase[(long long)(m0 + rl) * CDIM + h * HD + d] =
                    f2bf(acc[tm][tn][r] * rinv[tm][r]);
            }
    if (which == 2) {
        // x_ori (raw f32) + stage raw bf16 into T for the Vt transpose
#pragma unroll
        for (int tm = 0; tm < 4; tm++)
#pragma unroll
            for (int tn = 0; tn < 4; tn++)
#pragma unroll
                for (int r = 0; r < 4; r++) {
                    int rl = wm * 64 + tm * 16 + q * 4 + r;
                    int d = wn * 64 + tn * 16 + l16;
                    float v = acc[tm][tn][r];
                    out[(long long)(m0 + rl) * 2048 + 1024 + h * HD + d] = v;
                    T[rl * 136 + d] = f2bf(v);
                }
        __syncthreads();
        // coalesced Vt store: Vt[h*HD+drow][m0..m0+127]
#pragma unroll
        for (int p = 0; p < 2; p++) {
            int drow = p * 64 + (tid >> 2);
            int nc = (tid & 3) * 32;
            u16 buf[32];
#pragma unroll
            for (int i = 0; i < 32; i++) buf[i] = T[(nc + i) * 136 + drow];
            u16* dst = &Vt[(long long)(h * HD + drow) * NTOK + m0 + nc];
            *(short8*)&dst[0] = *(short8*)&buf[0];
            *(short8*)&dst[8] = *(short8*)&buf[8];
            *(short8*)&dst[16] = *(short8*)&buf[16];
            *(short8*)&dst[24] = *(short8*)&buf[24];
        }
    }
}

// ---------------------------------------------------------------- K1b: sim-mask GEMM
// R13: 128x64 tiles, full 32x16 grid (512 blocks = 2/CU), no mirror.
// R14/R15: + XCD-chunked swizzle (bijective), output-1 only.
__global__ __launch_bounds__(256) void k_gemm_mask(const u16* __restrict__ A,
                                                   const u16* __restrict__ B,
                                                   unsigned char* __restrict__ Cv,
                                                   int K, int lda, int ldb, int ldc,
                                                   float scale) {
    __shared__ u16 As2[2][8192];   // 128 x 64
    __shared__ u16 Bs2[2][4096];   //  64 x 64
    __shared__ __attribute__((aligned(16))) unsigned char Tm[128][80];
    const int tid = threadIdx.x;
    const int lane = tid & 63;
    const int wid = tid >> 6;
    const int wm = wid >> 1, wn = wid & 1;
    const int q = lane >> 4, l16 = lane & 15;
    const int bid = blockIdx.x + 32 * blockIdx.y;   // 0..511
    const int sw = (bid & 7) * 64 + (bid >> 3);
    const int m0 = (sw >> 5) * 128, n0 = (sw & 31) * 64;

    const u16* aP[4];
    const u16* bP[2];
#pragma unroll
    for (int t = 0; t < 4; t++) {
        int s = tid + t * 256;
        aP[t] = &A[(long long)(m0 + (s >> 3)) * lda + (s & 7) * 8];
    }
#pragma unroll
    for (int t = 0; t < 2; t++) {
        int s = tid + t * 256;
        bP[t] = &B[(long long)(n0 + (s >> 3)) * ldb + (s & 7) * 8];
    }
    // prologue: tile 0 into buffer 0
#pragma unroll
    for (int t = 0; t < 4; t++) { gld_lds16(aP[t], &As2[0][(tid + t * 256) * 8]); aP[t] += 64; }
#pragma unroll
    for (int t = 0; t < 2; t++) { gld_lds16(bP[t], &Bs2[0][(tid + t * 256) * 8]); bP[t] += 64; }

    f32x4 zero4 = {0.f, 0.f, 0.f, 0.f};
    f32x4 acc[4][2];
#pragma unroll
    for (int i = 0; i < 4; i++)
#pragma unroll
        for (int j = 0; j < 2; j++) acc[i][j] = zero4;

    const int NIT = K / 64;
    for (int jt = 0; jt < NIT; ++jt) {
        const u16* As = As2[jt & 1];
        const u16* Bs = Bs2[jt & 1];
        asm volatile("s_waitcnt vmcnt(0)" ::: "memory");
        __builtin_amdgcn_s_barrier();
        asm volatile("" ::: "memory");
        if (jt < NIT - 1) {
            u16* Ax = As2[(jt + 1) & 1];
            u16* Bx = Bs2[(jt + 1) & 1];
#pragma unroll
            for (int t = 0; t < 4; t++) { gld_lds16(aP[t], &Ax[(tid + t * 256) * 8]); aP[t] += 64; }
#pragma unroll
            for (int t = 0; t < 2; t++) { gld_lds16(bP[t], &Bx[(tid + t * 256) * 8]); bP[t] += 64; }
        }
#pragma unroll
        for (int ks = 0; ks < 2; ks++) {
            short8 af[4], bfr[2];
#pragma unroll
            for (int tm = 0; tm < 4; tm++)
                af[tm] = *(const short8*)&As[(wm * 64 + tm * 16 + l16) * 64 + ks * 32 + q * 8];
#pragma unroll
            for (int tn = 0; tn < 2; tn++)
                bfr[tn] = *(const short8*)&Bs[(wn * 32 + tn * 16 + l16) * 64 + ks * 32 + q * 8];
#pragma unroll
            for (int tm = 0; tm < 4; tm++)
#pragma unroll
                for (int tn = 0; tn < 2; tn++)
                    acc[tm][tn] = __builtin_amdgcn_mfma_f32_16x16x32_bf16(
                        af[tm], bfr[tn], acc[tm][tn], 0, 0, 0);
        }
    }

    // stage mask bits in LDS (own orientation only), then coalesced store
#pragma unroll
    for (int tm = 0; tm < 4; tm++)
#pragma unroll
        for (int tn = 0; tn < 2; tn++) {
            int col = wn * 32 + tn * 16 + l16;
            int rowbase = wm * 64 + tm * 16 + q * 4;
#pragma unroll
            for (int r = 0; r < 4; r++)
                Tm[rowbase + r][col] = (acc[tm][tn][r] * scale > 0.75f) ? 1 : 0;
        }
    __syncthreads();
    {
        int row = tid >> 1, half = (tid & 1) * 32;
        const short8* sm = (const short8*)&Tm[row][half];
        short8* dm = (short8*)&Cv[(long long)(m0 + row) * ldc + n0 + half];
        dm[0] = sm[0]; dm[1] = sm[1];
    }
}

// ---------------------------------------------------------------- K3: fused QK->exp->P + PV
// R18-proven structure (FROZEN geometry: 128-row i-tile, dbuf DMA, counted
// vmcnt, setprio, XCD swizzle, coalesced P-store, folded mask).
// R21: per-block j-tile PHASE ROTATION. Hypothesis: the 2 co-resident blocks
// per CU are phase-locked (identical loop + barrier cadence, simultaneous
// launch) so both starve at the same time; rotating each block's j-tile
// visiting order (jtp = (jt+phase)&7) decorrelates their barrier phases so
// one block computes while the other drains. phase is XOR-folded from bid so
// any plausible co-resident pairing (bid+-1, bid+-256) gets distinct phases.
// Numerics: sums/pv accumulate the same 512 j-terms in rotated order (f32
// reorder ~1e-6 rel); P slices order-independent; outputs disjoint.
__global__ __launch_bounds__(256, 2) void k_attn9(const u16* __restrict__ Qn,
                                                  const u16* __restrict__ Kn,
                                                  const u16* __restrict__ Vt,
                                                  const float* __restrict__ cls,
                                                  u16* __restrict__ P,
                                                  float* __restrict__ Spart,
                                                  u16* __restrict__ Xpart) {
    __shared__ u16 Kf[2][8192];  // QK B-frags, dbuf, 16 groups: slot ((tn*4+kt)*64+lane)*8
    __shared__ u16 Vf[2][8192];  // PV B-frags, dbuf, 16 groups: slot ((n*2+ks)*64+lane)*8
    __shared__ u16 Et[8192];     // e tile 128x64 bf16, XOR-chunk swizzled
    const int bid = blockIdx.x + 16 * (blockIdx.y + 4 * blockIdx.z);  // 0..511
    const int sw = (bid & 7) * 64 + (bid >> 3);
    const int h = sw >> 6;
    const int jc = (sw >> 4) & 3;
    const int i0 = (sw & 15) * 128;
    const int jbase = jc * 512;
    const int phase = (bid ^ (bid >> 3) ^ (bid >> 6)) & 7;  // R21 decorrelator
    const int tid = threadIdx.x, lane = tid & 63, wid = tid >> 6;
    const int q = lane >> 4, l16 = lane & 15;
    const int wm = wid >> 1, wn = wid & 1;

    // resident Q fragments (i range: wm*64 .. +63)
    short8 af[4][4];
#pragma unroll
    for (int m = 0; m < 4; m++)
#pragma unroll
        for (int kt = 0; kt < 4; kt++)
            af[m][kt] = *(const short8*)&Qn[(long long)(i0 + wm * 64 + m * 16 + l16) * CDIM +
                                            h * HD + kt * 32 + q * 8];
    float cls_i[4][4];
#pragma unroll
    for (int m = 0; m < 4; m++)
#pragma unroll
        for (int r = 0; r < 4; r++)
            cls_i[m][r] = cls[i0 + wm * 64 + m * 16 + q * 4 + r] - 0.1f;

    // DMA gather BASE sources (at jbase); per-tile offset applied per prefetch.
    const u16* ksrcB[4];
    const u16* vsrcB[4];
#pragma unroll
    for (int t = 0; t < 4; t++) {
        int g = wid * 4 + t;
        int tn = g >> 2, kt = g & 3;
        ksrcB[t] = &Kn[(long long)(jbase + tn * 16 + l16) * CDIM + h * HD + kt * 32 + q * 8];
        int n = g >> 1, ks = g & 1;
        vsrcB[t] = &Vt[(long long)(h * HD + n * 16 + l16) * NTOK + jbase + (ks * 4 + q) * 8];
    }

    f32x4 zero4 = {0.f, 0.f, 0.f, 0.f};
    f32x4 pv[4][4];
#pragma unroll
    for (int m = 0; m < 4; m++)
#pragma unroll
        for (int n = 0; n < 4; n++) pv[m][n] = zero4;
    float sums[4][4];
#pragma unroll
    for (int m = 0; m < 4; m++)
#pragma unroll
        for (int r = 0; r < 4; r++) sums[m][r] = 0.f;

    // prologue: prefetch tile `phase` into buffer 0
#pragma unroll
    for (int t = 0; t < 4; t++) {
        int g = wid * 4 + t;
        gld_lds16(ksrcB[t] + phase * 64 * CDIM, &Kf[0][(g * 64 + lane) * 8]);
        gld_lds16(vsrcB[t] + phase * 64, &Vf[0][(g * 64 + lane) * 8]);
    }

    for (int jt = 0; jt < 8; ++jt) {
        const int jtp = (jt + phase) & 7;       // rotated tile index
        const int j0 = jbase + jtp * 64;
        const int cur = jt & 1;
        u16* Kc = Kf[cur];
        // wait own 8 DMAs for buf[cur]; tolerate the 4 newest VMEM (P-stores)
        if (jt == 0)
            asm volatile("s_waitcnt vmcnt(0)" ::: "memory");
        else
            asm volatile("s_waitcnt vmcnt(4)" ::: "memory");
        // cls loads for THIS tile, issued before the prefetch DMAs so their
        // consumption does not drain the DMA queue (in-order vmcnt).
        float cjv[2];
        cjv[0] = cls[j0 + (wn * 2 + 0) * 16 + l16];
        cjv[1] = cls[j0 + (wn * 2 + 1) * 16 + l16];
        asm volatile("" ::: "memory");
        __builtin_amdgcn_s_barrier();   // all waves' DMAs landed; prev Et consumers done
        asm volatile("" ::: "memory");
        if (jt < 7) {  // issue next tile's DMAs into the other buffer NOW
            const int ntile = (jt + 1 + phase) & 7;
            u16* Kx = Kf[cur ^ 1];
            u16* Vx = Vf[cur ^ 1];
#pragma unroll
            for (int t = 0; t < 4; t++) {
                int g = wid * 4 + t;
                gld_lds16(ksrcB[t] + ntile * 64 * CDIM, &Kx[(g * 64 + lane) * 8]);
                gld_lds16(vsrcB[t] + ntile * 64, &Vx[(g * 64 + lane) * 8]);
            }
        }
        // QK -> e -> Et (+ row sums)
#pragma unroll
        for (int tn = 0; tn < 2; tn++) {
            int tng = wn * 2 + tn;
            short8 bfr[4];
#pragma unroll
            for (int kt = 0; kt < 4; kt++)
                bfr[kt] = *(const short8*)&Kc[((tng * 4 + kt) * 64 + lane) * 8];
            float cj = cjv[tn];
            float sc = 25.f * cj;
#pragma unroll
            for (int m = 0; m < 4; m++) {
                f32x4 acc = zero4;
                __builtin_amdgcn_s_setprio(1);
#pragma unroll
                for (int kt = 0; kt < 4; kt++)
                    acc = __builtin_amdgcn_mfma_f32_16x16x32_bf16(af[m][kt], bfr[kt],
                                                                  acc, 0, 0, 0);
                __builtin_amdgcn_s_setprio(0);
                int ibase = wm * 64 + m * 16 + q * 4;
#pragma unroll
                for (int r = 0; r < 4; r++) {
                    float arg = (cj > cls_i[m][r]) ? acc[r] * sc : 0.f;
                    float e = __expf(arg);
                    sums[m][r] += e;
                    int il = ibase + r;
                    int jl = tng * 16 + l16;
                    Et[il * 64 + ((((jl >> 3) ^ (il & 7)) << 3) | (jl & 7))] = f2bf(e);
                }
            }
        }
        asm volatile("s_waitcnt lgkmcnt(0)" ::: "memory");  // own Et writes committed
        __builtin_amdgcn_s_barrier();                       // all waves' Et visible
        asm volatile("" ::: "memory");
        {   // P store from Et: 8 lanes/row -> 8 contiguous 128B segments/instr
#pragma unroll
            for (int k = 0; k < 4; k++) {
                int il = k * 32 + (tid >> 3);
                int c = tid & 7;
                short8 ev = *(const short8*)&Et[il * 64 + ((c ^ (il & 7)) << 3)];
                *(short8*)&P[((long long)(h * NTOK + i0 + il)) * NTOK + j0 + c * 8] = ev;
            }
        }
        // PV: A from Et (swizzled), B from Vf; out tile i(128) x d(128)
        __builtin_amdgcn_s_setprio(1);
#pragma unroll
        for (int ks = 0; ks < 2; ks++) {
            short8 a2[4];
#pragma unroll
            for (int m2 = 0; m2 < 4; m2++) {
                int il = wm * 64 + m2 * 16 + l16;
                int ch = ks * 4 + q;
                a2[m2] = *(const short8*)&Et[il * 64 + ((ch ^ (il & 7)) << 3)];
            }
#pragma unroll
            for (int n2 = 0; n2 < 4; n2++) {
                short8 b2 = *(const short8*)&Vf[cur][(((wn * 4 + n2) * 2 + ks) * 64 + lane) * 8];
#pragma unroll
                for (int m2 = 0; m2 < 4; m2++)
                    pv[m2][n2] = __builtin_amdgcn_mfma_f32_16x16x32_bf16(
                        a2[m2], b2, pv[m2][n2], 0, 0, 0);
            }
        }
        __builtin_amdgcn_s_setprio(0);
    }
    // row-sum partials (race-free: one writer per (wn,jc,h,row))
#pragma unroll
    for (int m = 0; m < 4; m++)
#pragma unroll
        for (int r = 0; r < 4; r++) {
            float s = sums[m][r];
            s += __shfl_xor(s, 1);
            s += __shfl_xor(s, 2);
            s += __shfl_xor(s, 4);
            s += __shfl_xor(s, 8);
            if (l16 == 0)
                Spart[((wn * 4 + jc) * NH + h) * NTOK + i0 + wm * 64 + m * 16 + q * 4 + r] = s;
        }
    // store PV partial to this jc's slab (bf16, plain stores, no atomics)
    u16* Xp = Xpart + (long long)jc * NTOK * CDIM;
#pragma unroll
    for (int m2 = 0; m2 < 4; m2++)
#pragma unroll
        for (int n2 = 0; n2 < 4; n2++)
#pragma unroll
            for (int r = 0; r < 4; r++) {
                int i = i0 + wm * 64 + m2 * 16 + q * 4 + r;
                int d = wn * 64 + n2 * 16 + l16;
                Xp[(long long)i * CDIM + h * HD + d] = f2bf(pv[m2][n2][r]);
            }
}

// ---------------------------------------------------------------- K4: merged epilogue: x=(sum Xpart)/S  and  output2
// R17: wave butterfly + 4-slot combine (neutral vs 8-step tree; kept).
__global__ __launch_bounds__(256) void k_epi(const u16* __restrict__ Xpart,
                                             const float* __restrict__ Spart,
                                             const u16* __restrict__ P,
                                             const unsigned char* __restrict__ mask,
                                             float* __restrict__ out,
                                             float* __restrict__ out2) {
    __shared__ float redw[4];
    __shared__ float sArr[NH];
    const int i = blockIdx.x;
    const int t = threadIdx.x;
    const int lane = t & 63, w4 = t >> 6;
    if (t < NH) {
        float s = 0.f;
#pragma unroll
        for (int g = 0; g < 8; g++) s += Spart[(g * NH + t) * NTOK + i];
        sArr[t] = s;
    }
    __syncthreads();
    // ---- part A: x row i (1024 cols, 4 per thread)
    {
        int c = t * 4;
        int h = c >> 7;
        float acc[4] = {0.f, 0.f, 0.f, 0.f};
#pragma unroll
        for (int jc = 0; jc < 4; jc++) {
            short4v v = *(const short4v*)&Xpart[(long long)jc * NTOK * CDIM +
                                                (long long)i * CDIM + c];
#pragma unroll
            for (int k = 0; k < 4; k++) acc[k] += bf2f((u16)v[k]);
        }
        float invs = 1.f / sArr[h];
        float4 o;
        o.x = acc[0] * invs; o.y = acc[1] * invs; o.z = acc[2] * invs; o.w = acc[3] * invs;
        *(float4*)&out[(long long)i * 2048 + c] = o;
    }
    // ---- part B: output2 row i (2048 cols, 8 per thread)
    float invS[NH];
#pragma unroll
    for (int h = 0; h < NH; h++) invS[h] = 1.f / (8.f * sArr[h]);
    const int c0 = t * 8;
    float a[8] = {0.f, 0.f, 0.f, 0.f, 0.f, 0.f, 0.f, 0.f};
#pragma unroll
    for (int h = 0; h < NH; h++) {
        short8 p = *(const short8*)&P[((long long)h * NTOK + i) * NTOK + c0];
#pragma unroll
        for (int k = 0; k < 8; k++) a[k] += bf2f((u16)p[k]) * invS[h];
    }
    uint2 mv = *(const uint2*)(mask + (long long)i * NTOK + c0);  // 8B-aligned
    unsigned char mk[8];
#pragma unroll
    for (int k = 0; k < 4; k++) {
        mk[k] = (unsigned char)((mv.x >> (8 * k)) & 0xffu);
        mk[k + 4] = (unsigned char)((mv.y >> (8 * k)) & 0xffu);
    }
    float e[8];
    float part = 0.f;
#pragma unroll
    for (int k = 0; k < 8; k++) {
        e[k] = __expf(a[k]);
        if (mk[k]) part += e[k];
    }
    // wave butterfly + cross-wave combine (single barrier)
    part += __shfl_xor(part, 1);
    part += __shfl_xor(part, 2);
    part += __shfl_xor(part, 4);
    part += __shfl_xor(part, 8);
    part += __shfl_xor(part, 16);
    part += __shfl_xor(part, 32);
    if (lane == 0) redw[w4] = part;
    __syncthreads();
    float tot = (redw[0] + redw[1]) + (redw[2] + redw[3]);
    float invT = 1.f / tot;
    float o[8];
#pragma unroll
    for (int k = 0; k < 8; k++) o[k] = mk[k] ? e[k] * invT : 0.f;
    float4 o0, o1;
    o0.x = o[0]; o0.y = o[1]; o0.z = o[2]; o0.w = o[3];
    o1.x = o[4]; o1.y = o[5]; o1.z = o[6]; o1.w = o[7];
    float* dst = out2 + (long long)i * NTOK + c0;
    *(float4*)dst = o0;
    *(float4*)(dst + 4) = o1;
}

// ---------------------------------------------------------------- launcher
extern "C" void kernel_launch(void* const* d_in, const int* in_sizes, int n_in,
                              void* d_out, int out_size, void* d_ws,
                              size_t ws_size, hipStream_t stream) {
    (void)in_sizes; (void)n_in; (void)out_size; (void)ws_size;
    const float* x = (const float*)d_in[0];
    const float* cls = (const float*)d_in[1];
    // d_in[2] = fg_score: unused by the reference
    const float* Wq = (const float*)d_in[3];
    float* out = (float*)d_out;
    char* ws = (char*)d_ws;

    // Region [0, 23068672): early buffers (Xb/Wb dead after k_qkvn) overlaid
    // with Xpart/Spart (written only by k_attn9 afterwards).
    u16* Xb = (u16*)(ws + 0);                      //  4 MB  [2048,1024]
    u16* Wb = (u16*)(ws + 4194304);                //  6 MB  [3072,1024]
    u16* Xpart = (u16*)(ws + 0);                   // 16 MB  [4][2048,1024] bf16 PV partials
    float* Spart = (float*)(ws + 16777216);        // 512 KB [8][8,2048] row-sum partials
    u16* Qn = (u16*)(ws + 23068672);               //  4 MB
    u16* Kn = (u16*)(ws + 27262976);               //  4 MB
    u16* Vn = (u16*)(ws + 31457280);               //  4 MB
    u16* Vt = (u16*)(ws + 35651584);               //  4 MB  [1024,2048]
    unsigned char* mask = (unsigned char*)(ws + 39845888);  // 4 MB [2048,2048]
    u16* P = (u16*)(ws + 44040192);                // 67 MB [8,2048,2048]

    // 1. cast x and W to bf16
    k_cast<<<1024, 256, 0, stream>>>(x, Wq, Xb, Wb);

    // 2. fused QKV GEMM + norm + x_ori + Vt (R13-proven 384-block version)
    k_qkvn<<<dim3(24, 16), 256, 0, stream>>>(Xb, Wb, Qn, Kn, Vn, Vt, out);

    // 3. sim mask = (Vn @ Vn^T / 8 > 0.75) -> u8, full grid 128x64 tiles
    k_gemm_mask<<<dim3(32, 16), 256, 0, stream>>>(
        Vn, Vn, mask, CDIM, CDIM, CDIM, NTOK, 0.125f);

    // 4. fused logits+exp -> P, partial row sums, partial PV -> Xpart
    k_attn9<<<dim3(16, 4, NH), 256, 0, stream>>>(Qn, Kn, Vt, cls, P, Spart, Xpart);

    // 5. merged epilogue: x and output2
    k_epi<<<NTOK, 256, 0, stream>>>(Xpart, Spart, P, mask, out,
                                    out + (long long)NTOK * 2048);
}

// Round 14
// 185.777 us; speedup vs baseline: 1.0133x; 1.0133x over previous
//
#include <hip/hip_runtime.h>
#include <cstdint>

typedef unsigned short u16;
typedef __attribute__((ext_vector_type(8))) short short8;
typedef __attribute__((ext_vector_type(4))) short short4v;
typedef __attribute__((ext_vector_type(4))) float f32x4;

#define NTOK 2048
#define CDIM 1024
#define C3   3072
#define NH   8
#define HD   128

__device__ __forceinline__ float bf2f(u16 u) {
    return __uint_as_float(((unsigned)u) << 16);
}
__device__ __forceinline__ u16 f2bf(float f) {
    unsigned u = __float_as_uint(f);
    u += 0x7fffu + ((u >> 16) & 1u);
    return (u16)(u >> 16);
}
// async 16B global->LDS DMA; LDS dest must be wave-uniform base + lane*16
__device__ __forceinline__ void gld_lds16(const u16* g, u16* l) {
    __builtin_amdgcn_global_load_lds(
        (__attribute__((address_space(1))) void*)(u16*)g,
        (__attribute__((address_space(3))) void*)l, 16, 0, 0);
}

// ---------------------------------------------------------------- K0: f32->bf16
__global__ __launch_bounds__(256) void k_cast(const float* __restrict__ x,
                                              const float* __restrict__ w,
                                              u16* __restrict__ xb,
                                              u16* __restrict__ wb) {
    int t = blockIdx.x * blockDim.x + threadIdx.x;
    int stride = gridDim.x * blockDim.x;
    for (int i = t; i < (NTOK * CDIM) / 4; i += stride) {
        float4 v = ((const float4*)x)[i];
        ushort4 o;
        o.x = f2bf(v.x); o.y = f2bf(v.y); o.z = f2bf(v.z); o.w = f2bf(v.w);
        ((ushort4*)xb)[i] = o;
    }
    for (int i = t; i < (C3 * CDIM) / 4; i += stride) {
        float4 v = ((const float4*)w)[i];
        ushort4 o;
        o.x = f2bf(v.x); o.y = f2bf(v.y); o.z = f2bf(v.z); o.w = f2bf(v.w);
        ((ushort4*)wb)[i] = o;
    }
}

// ---------------------------------------------------------------- K1: fused QKV GEMM + norm/x_ori/Vt epilogue
// R13 VERSION (verified). Single-barrier double-buffered DMA K-loop.
// R14 NOTE: BM=64 balanced-grid rewrite FAILED (absmax 1.68, output 0);
// reverted. Do not retry without host-side unit test of the index mapping.
__global__ __launch_bounds__(256) void k_qkvn(const u16* __restrict__ A,
                                              const u16* __restrict__ B,
                                              u16* __restrict__ Qn,
                                              u16* __restrict__ Kn,
                                              u16* __restrict__ Vn,
                                              u16* __restrict__ Vt,
                                              float* __restrict__ out) {
    __shared__ u16 SB[2][16384];     // per buf: As = [0:8192], Bs = [8192:16384]
    __shared__ float rowssq[128][2];
    u16* T = (u16*)SB;               // epilogue reuse: T[128][136] (34.8 KB)
    const int tid = threadIdx.x;
    const int lane = tid & 63;
    const int wid = tid >> 6;
    const int wm = wid >> 1, wn = wid & 1;
    const int q = lane >> 4, l16 = lane & 15;
    const int s = blockIdx.x;            // head-slice 0..23
    const int which = s >> 3, h = s & 7; // 0=q 1=k 2=v
    const int m0 = blockIdx.y * 128, n0 = s * 128;

    const u16* aP[4];
    const u16* bP[4];
#pragma unroll
    for (int t = 0; t < 4; t++) {
        int sl = tid + t * 256;
        int r = sl >> 3, c = (sl & 7) * 8;
        aP[t] = &A[(long long)(m0 + r) * CDIM + c];
        bP[t] = &B[(long long)(n0 + r) * CDIM + c];
    }
    // prologue: tile 0 into buffer 0
#pragma unroll
    for (int t = 0; t < 4; t++) {
        int sl = tid + t * 256;
        gld_lds16(aP[t], &SB[0][sl * 8]);
        gld_lds16(bP[t], &SB[0][8192 + sl * 8]);
        aP[t] += 64;
        bP[t] += 64;
    }

    f32x4 zero4 = {0.f, 0.f, 0.f, 0.f};
    f32x4 acc[4][4];
#pragma unroll
    for (int i = 0; i < 4; i++)
#pragma unroll
        for (int j = 0; j < 4; j++) acc[i][j] = zero4;

    for (int jt = 0; jt < 16; ++jt) {
        const u16* As = SB[jt & 1];
        const u16* Bs = SB[jt & 1] + 8192;
        asm volatile("s_waitcnt vmcnt(0)" ::: "memory");  // own DMAs for buf[cur]
        __builtin_amdgcn_s_barrier();                     // all waves' DMAs landed
        asm volatile("" ::: "memory");
        if (jt < 15) {   // issue next tile into the other buffer NOW
            u16* Sx = SB[(jt + 1) & 1];
#pragma unroll
            for (int t = 0; t < 4; t++) {
                int sl = tid + t * 256;
                gld_lds16(aP[t], &Sx[sl * 8]);
                gld_lds16(bP[t], &Sx[8192 + sl * 8]);
                aP[t] += 64;
                bP[t] += 64;
            }
        }
#pragma unroll
        for (int ks = 0; ks < 2; ks++) {
            short8 af[4], bfr[4];
#pragma unroll
            for (int tm = 0; tm < 4; tm++)
                af[tm] = *(const short8*)&As[(wm * 64 + tm * 16 + l16) * 64 + ks * 32 + q * 8];
#pragma unroll
            for (int tn = 0; tn < 4; tn++)
                bfr[tn] = *(const short8*)&Bs[(wn * 64 + tn * 16 + l16) * 64 + ks * 32 + q * 8];
#pragma unroll
            for (int tm = 0; tm < 4; tm++)
#pragma unroll
                for (int tn = 0; tn < 4; tn++)
                    acc[tm][tn] = __builtin_amdgcn_mfma_f32_16x16x32_bf16(
                        af[tm], bfr[tn], acc[tm][tn], 0, 0, 0);
        }
    }

    __syncthreads();  // all LDS reads done; SB reusable as T, rowssq writable
    // per-row sum of squares: this wave's 64-col half, then cross-wave via LDS
#pragma unroll
    for (int tm = 0; tm < 4; tm++)
#pragma unroll
        for (int r = 0; r < 4; r++) {
            float p = 0.f;
#pragma unroll
            for (int tn = 0; tn < 4; tn++) p += acc[tm][tn][r] * acc[tm][tn][r];
            p += __shfl_xor(p, 1);
            p += __shfl_xor(p, 2);
            p += __shfl_xor(p, 4);
            p += __shfl_xor(p, 8);
            if (l16 == 0) rowssq[wm * 64 + tm * 16 + q * 4 + r][wn] = p;
        }
    __syncthreads();
    float rinv[4][4];
#pragma unroll
    for (int tm = 0; tm < 4; tm++)
#pragma unroll
        for (int r = 0; r < 4; r++) {
            int rl = wm * 64 + tm * 16 + q * 4 + r;
            rinv[tm][r] = rsqrtf(rowssq[rl][0] + rowssq[rl][1]);
        }
    // normalized bf16 store to Qn/Kn/Vn
    u16* dstBase = (which == 0 ? Qn : which == 1 ? Kn : Vn);
#pragma unroll
    for (int tm = 0; tm < 4; tm++)
#pragma unroll
        for (int tn = 0; tn < 4; tn++)
#pragma unroll
            for (int r = 0; r < 4; r++) {
                int rl = wm * 64 + tm * 16 + q * 4 + r;
                int d = wn * 64 + tn * 16 + l16;
                dstBase[(long long)(m0 + rl) * CDIM + h * HD + d] =
                    f2bf(acc[tm][tn][r] * rinv[tm][r]);
            }
    if (which == 2) {
        // x_ori (raw f32) + stage raw bf16 into T for the Vt transpose
#pragma unroll
        for (int tm = 0; tm < 4; tm++)
#pragma unroll
            for (int tn = 0; tn < 4; tn++)
#pragma unroll
                for (int r = 0; r < 4; r++) {
                    int rl = wm * 64 + tm * 16 + q * 4 + r;
                    int d = wn * 64 + tn * 16 + l16;
                    float v = acc[tm][tn][r];
                    out[(long long)(m0 + rl) * 2048 + 1024 + h * HD + d] = v;
                    T[rl * 136 + d] = f2bf(v);
                }
        __syncthreads();
        // coalesced Vt store: Vt[h*HD+drow][m0..m0+127]
#pragma unroll
        for (int p = 0; p < 2; p++) {
            int drow = p * 64 + (tid >> 2);
            int nc = (tid & 3) * 32;
            u16 buf[32];
#pragma unroll
            for (int i = 0; i < 32; i++) buf[i] = T[(nc + i) * 136 + drow];
            u16* dst = &Vt[(long long)(h * HD + drow) * NTOK + m0 + nc];
            *(short8*)&dst[0] = *(short8*)&buf[0];
            *(short8*)&dst[8] = *(short8*)&buf[8];
            *(short8*)&dst[16] = *(short8*)&buf[16];
            *(short8*)&dst[24] = *(short8*)&buf[24];
        }
    }
}

// ---------------------------------------------------------------- K1b: sim-mask GEMM
// R13: 128x64 tiles, full 32x16 grid (512 blocks = 2/CU), no mirror.
// R14/R15: + XCD-chunked swizzle (bijective), output-1 only.
__global__ __launch_bounds__(256) void k_gemm_mask(const u16* __restrict__ A,
                                                   const u16* __restrict__ B,
                                                   unsigned char* __restrict__ Cv,
                                                   int K, int lda, int ldb, int ldc,
                                                   float scale) {
    __shared__ u16 As2[2][8192];   // 128 x 64
    __shared__ u16 Bs2[2][4096];   //  64 x 64
    __shared__ __attribute__((aligned(16))) unsigned char Tm[128][80];
    const int tid = threadIdx.x;
    const int lane = tid & 63;
    const int wid = tid >> 6;
    const int wm = wid >> 1, wn = wid & 1;
    const int q = lane >> 4, l16 = lane & 15;
    const int bid = blockIdx.x + 32 * blockIdx.y;   // 0..511
    const int sw = (bid & 7) * 64 + (bid >> 3);
    const int m0 = (sw >> 5) * 128, n0 = (sw & 31) * 64;

    const u16* aP[4];
    const u16* bP[2];
#pragma unroll
    for (int t = 0; t < 4; t++) {
        int s = tid + t * 256;
        aP[t] = &A[(long long)(m0 + (s >> 3)) * lda + (s & 7) * 8];
    }
#pragma unroll
    for (int t = 0; t < 2; t++) {
        int s = tid + t * 256;
        bP[t] = &B[(long long)(n0 + (s >> 3)) * ldb + (s & 7) * 8];
    }
    // prologue: tile 0 into buffer 0
#pragma unroll
    for (int t = 0; t < 4; t++) { gld_lds16(aP[t], &As2[0][(tid + t * 256) * 8]); aP[t] += 64; }
#pragma unroll
    for (int t = 0; t < 2; t++) { gld_lds16(bP[t], &Bs2[0][(tid + t * 256) * 8]); bP[t] += 64; }

    f32x4 zero4 = {0.f, 0.f, 0.f, 0.f};
    f32x4 acc[4][2];
#pragma unroll
    for (int i = 0; i < 4; i++)
#pragma unroll
        for (int j = 0; j < 2; j++) acc[i][j] = zero4;

    const int NIT = K / 64;
    for (int jt = 0; jt < NIT; ++jt) {
        const u16* As = As2[jt & 1];
        const u16* Bs = Bs2[jt & 1];
        asm volatile("s_waitcnt vmcnt(0)" ::: "memory");
        __builtin_amdgcn_s_barrier();
        asm volatile("" ::: "memory");
        if (jt < NIT - 1) {
            u16* Ax = As2[(jt + 1) & 1];
            u16* Bx = Bs2[(jt + 1) & 1];
#pragma unroll
            for (int t = 0; t < 4; t++) { gld_lds16(aP[t], &Ax[(tid + t * 256) * 8]); aP[t] += 64; }
#pragma unroll
            for (int t = 0; t < 2; t++) { gld_lds16(bP[t], &Bx[(tid + t * 256) * 8]); bP[t] += 64; }
        }
#pragma unroll
        for (int ks = 0; ks < 2; ks++) {
            short8 af[4], bfr[2];
#pragma unroll
            for (int tm = 0; tm < 4; tm++)
                af[tm] = *(const short8*)&As[(wm * 64 + tm * 16 + l16) * 64 + ks * 32 + q * 8];
#pragma unroll
            for (int tn = 0; tn < 2; tn++)
                bfr[tn] = *(const short8*)&Bs[(wn * 32 + tn * 16 + l16) * 64 + ks * 32 + q * 8];
#pragma unroll
            for (int tm = 0; tm < 4; tm++)
#pragma unroll
                for (int tn = 0; tn < 2; tn++)
                    acc[tm][tn] = __builtin_amdgcn_mfma_f32_16x16x32_bf16(
                        af[tm], bfr[tn], acc[tm][tn], 0, 0, 0);
        }
    }

    // stage mask bits in LDS (own orientation only), then coalesced store
#pragma unroll
    for (int tm = 0; tm < 4; tm++)
#pragma unroll
        for (int tn = 0; tn < 2; tn++) {
            int col = wn * 32 + tn * 16 + l16;
            int rowbase = wm * 64 + tm * 16 + q * 4;
#pragma unroll
            for (int r = 0; r < 4; r++)
                Tm[rowbase + r][col] = (acc[tm][tn][r] * scale > 0.75f) ? 1 : 0;
        }
    __syncthreads();
    {
        int row = tid >> 1, half = (tid & 1) * 32;
        const short8* sm = (const short8*)&Tm[row][half];
        short8* dm = (short8*)&Cv[(long long)(m0 + row) * ldc + n0 + half];
        dm[0] = sm[0]; dm[1] = sm[1];
    }
}

// ---------------------------------------------------------------- K3: fused QK->exp->P + PV
// R18-PROVEN VERSION (47.0 us, bank-conflicts 0) -- FINAL. Experiment ledger:
// schedule wins (R10/R12/R13/R18) banked here; geometry alternatives (R14
// BM=64, R16 single-buf 4-blk, R19 no-staging) and phase decorrelation (R21)
// all refuted with causal counter stories. Remaining idle-issue is the
// per-block serial chain {barrier -> ds_read -> MFMA -> exp/f2bf -> barrier}
// at 2 blocks/CU; breaking it requires the HK-style 8-phase deep-pipeline
// rewrite (new template class). FROZEN.
__global__ __launch_bounds__(256, 2) void k_attn9(const u16* __restrict__ Qn,
                                                  const u16* __restrict__ Kn,
                                                  const u16* __restrict__ Vt,
                                                  const float* __restrict__ cls,
                                                  u16* __restrict__ P,
                                                  float* __restrict__ Spart,
                                                  u16* __restrict__ Xpart) {
    __shared__ u16 Kf[2][8192];  // QK B-frags, dbuf, 16 groups: slot ((tn*4+kt)*64+lane)*8
    __shared__ u16 Vf[2][8192];  // PV B-frags, dbuf, 16 groups: slot ((n*2+ks)*64+lane)*8
    __shared__ u16 Et[8192];     // e tile 128x64 bf16, XOR-chunk swizzled
    const int bid = blockIdx.x + 16 * (blockIdx.y + 4 * blockIdx.z);  // 0..511
    const int sw = (bid & 7) * 64 + (bid >> 3);
    const int h = sw >> 6;
    const int jc = (sw >> 4) & 3;
    const int i0 = (sw & 15) * 128;
    const int jbase = jc * 512;
    const int tid = threadIdx.x, lane = tid & 63, wid = tid >> 6;
    const int q = lane >> 4, l16 = lane & 15;
    const int wm = wid >> 1, wn = wid & 1;

    // resident Q fragments (i range: wm*64 .. +63)
    short8 af[4][4];
#pragma unroll
    for (int m = 0; m < 4; m++)
#pragma unroll
        for (int kt = 0; kt < 4; kt++)
            af[m][kt] = *(const short8*)&Qn[(long long)(i0 + wm * 64 + m * 16 + l16) * CDIM +
                                            h * HD + kt * 32 + q * 8];
    float cls_i[4][4];
#pragma unroll
    for (int m = 0; m < 4; m++)
#pragma unroll
        for (int r = 0; r < 4; r++)
            cls_i[m][r] = cls[i0 + wm * 64 + m * 16 + q * 4 + r] - 0.1f;

    // DMA gather sources: wave `wid` owns groups wid*4..wid*4+3 for Kf and Vf.
    const u16* ksrc[4];
    const u16* vsrc[4];
#pragma unroll
    for (int t = 0; t < 4; t++) {
        int g = wid * 4 + t;
        int tn = g >> 2, kt = g & 3;
        ksrc[t] = &Kn[(long long)(jbase + tn * 16 + l16) * CDIM + h * HD + kt * 32 + q * 8];
        int n = g >> 1, ks = g & 1;
        vsrc[t] = &Vt[(long long)(h * HD + n * 16 + l16) * NTOK + jbase + (ks * 4 + q) * 8];
    }

    f32x4 zero4 = {0.f, 0.f, 0.f, 0.f};
    f32x4 pv[4][4];
#pragma unroll
    for (int m = 0; m < 4; m++)
#pragma unroll
        for (int n = 0; n < 4; n++) pv[m][n] = zero4;
    float sums[4][4];
#pragma unroll
    for (int m = 0; m < 4; m++)
#pragma unroll
        for (int r = 0; r < 4; r++) sums[m][r] = 0.f;

    // prologue: prefetch tile 0 into buffer 0
#pragma unroll
    for (int t = 0; t < 4; t++) {
        int g = wid * 4 + t;
        gld_lds16(ksrc[t], &Kf[0][(g * 64 + lane) * 8]);
        gld_lds16(vsrc[t], &Vf[0][(g * 64 + lane) * 8]);
        ksrc[t] += 64 * CDIM;
        vsrc[t] += 64;
    }

    for (int jt = 0; jt < 8; ++jt) {
        const int j0 = jbase + jt * 64;
        const int cur = jt & 1;
        u16* Kc = Kf[cur];
        // wait own 8 DMAs for buf[cur]; tolerate the 4 newest VMEM (P-stores)
        if (jt == 0)
            asm volatile("s_waitcnt vmcnt(0)" ::: "memory");
        else
            asm volatile("s_waitcnt vmcnt(4)" ::: "memory");
        // cls loads for THIS tile, issued before the prefetch DMAs so their
        // consumption does not drain the DMA queue (in-order vmcnt).
        float cjv[2];
        cjv[0] = cls[j0 + (wn * 2 + 0) * 16 + l16];
        cjv[1] = cls[j0 + (wn * 2 + 1) * 16 + l16];
        asm volatile("" ::: "memory");
        __builtin_amdgcn_s_barrier();   // all waves' DMAs landed; prev Et consumers done
        asm volatile("" ::: "memory");
        if (jt < 7) {  // issue next tile's DMAs into the other buffer NOW
            u16* Kx = Kf[cur ^ 1];
            u16* Vx = Vf[cur ^ 1];
#pragma unroll
            for (int t = 0; t < 4; t++) {
                int g = wid * 4 + t;
                gld_lds16(ksrc[t], &Kx[(g * 64 + lane) * 8]);
                gld_lds16(vsrc[t], &Vx[(g * 64 + lane) * 8]);
                ksrc[t] += 64 * CDIM;
                vsrc[t] += 64;
            }
        }
        // QK -> e -> Et (+ row sums)
#pragma unroll
        for (int tn = 0; tn < 2; tn++) {
            int tng = wn * 2 + tn;
            short8 bfr[4];
#pragma unroll
            for (int kt = 0; kt < 4; kt++)
                bfr[kt] = *(const short8*)&Kc[((tng * 4 + kt) * 64 + lane) * 8];
            float cj = cjv[tn];
            float sc = 25.f * cj;
#pragma unroll
            for (int m = 0; m < 4; m++) {
                f32x4 acc = zero4;
                __builtin_amdgcn_s_setprio(1);
#pragma unroll
                for (int kt = 0; kt < 4; kt++)
                    acc = __builtin_amdgcn_mfma_f32_16x16x32_bf16(af[m][kt], bfr[kt],
                                                                  acc, 0, 0, 0);
                __builtin_amdgcn_s_setprio(0);
                int ibase = wm * 64 + m * 16 + q * 4;
#pragma unroll
                for (int r = 0; r < 4; r++) {
                    float arg = (cj > cls_i[m][r]) ? acc[r] * sc : 0.f;
                    float e = __expf(arg);
                    sums[m][r] += e;
                    int il = ibase + r;
                    int jl = tng * 16 + l16;
                    Et[il * 64 + ((((jl >> 3) ^ (il & 7)) << 3) | (jl & 7))] = f2bf(e);
                }
            }
        }
        asm volatile("s_waitcnt lgkmcnt(0)" ::: "memory");  // own Et writes committed
        __builtin_amdgcn_s_barrier();                       // all waves' Et visible
        asm volatile("" ::: "memory");
        {   // P store from Et: 8 lanes/row -> 8 contiguous 128B segments/instr
#pragma unroll
            for (int k = 0; k < 4; k++) {
                int il = k * 32 + (tid >> 3);
                int c = tid & 7;
                short8 ev = *(const short8*)&Et[il * 64 + ((c ^ (il & 7)) << 3)];
                *(short8*)&P[((long long)(h * NTOK + i0 + il)) * NTOK + j0 + c * 8] = ev;
            }
        }
        // PV: A from Et (swizzled), B from Vf; out tile i(128) x d(128)
        __builtin_amdgcn_s_setprio(1);
#pragma unroll
        for (int ks = 0; ks < 2; ks++) {
            short8 a2[4];
#pragma unroll
            for (int m2 = 0; m2 < 4; m2++) {
                int il = wm * 64 + m2 * 16 + l16;
                int ch = ks * 4 + q;
                a2[m2] = *(const short8*)&Et[il * 64 + ((ch ^ (il & 7)) << 3)];
            }
#pragma unroll
            for (int n2 = 0; n2 < 4; n2++) {
                short8 b2 = *(const short8*)&Vf[cur][(((wn * 4 + n2) * 2 + ks) * 64 + lane) * 8];
#pragma unroll
                for (int m2 = 0; m2 < 4; m2++)
                    pv[m2][n2] = __builtin_amdgcn_mfma_f32_16x16x32_bf16(
                        a2[m2], b2, pv[m2][n2], 0, 0, 0);
            }
        }
        __builtin_amdgcn_s_setprio(0);
    }
    // row-sum partials (race-free: one writer per (wn,jc,h,row))
#pragma unroll
    for (int m = 0; m < 4; m++)
#pragma unroll
        for (int r = 0; r < 4; r++) {
            float s = sums[m][r];
            s += __shfl_xor(s, 1);
            s += __shfl_xor(s, 2);
            s += __shfl_xor(s, 4);
            s += __shfl_xor(s, 8);
            if (l16 == 0)
                Spart[((wn * 4 + jc) * NH + h) * NTOK + i0 + wm * 64 + m * 16 + q * 4 + r] = s;
        }
    // store PV partial to this jc's slab (bf16, plain stores, no atomics)
    u16* Xp = Xpart + (long long)jc * NTOK * CDIM;
#pragma unroll
    for (int m2 = 0; m2 < 4; m2++)
#pragma unroll
        for (int n2 = 0; n2 < 4; n2++)
#pragma unroll
            for (int r = 0; r < 4; r++) {
                int i = i0 + wm * 64 + m2 * 16 + q * 4 + r;
                int d = wn * 64 + n2 * 16 + l16;
                Xp[(long long)i * CDIM + h * HD + d] = f2bf(pv[m2][n2][r]);
            }
}

// ---------------------------------------------------------------- K4: merged epilogue: x=(sum Xpart)/S  and  output2
// R17: wave butterfly + 4-slot combine (neutral vs 8-step tree; kept).
__global__ __launch_bounds__(256) void k_epi(const u16* __restrict__ Xpart,
                                             const float* __restrict__ Spart,
                                             const u16* __restrict__ P,
                                             const unsigned char* __restrict__ mask,
                                             float* __restrict__ out,
                                             float* __restrict__ out2) {
    __shared__ float redw[4];
    __shared__ float sArr[NH];
    const int i = blockIdx.x;
    const int t = threadIdx.x;
    const int lane = t & 63, w4 = t >> 6;
    if (t < NH) {
        float s = 0.f;
#pragma unroll
        for (int g = 0; g < 8; g++) s += Spart[(g * NH + t) * NTOK + i];
        sArr[t] = s;
    }
    __syncthreads();
    // ---- part A: x row i (1024 cols, 4 per thread)
    {
        int c = t * 4;
        int h = c >> 7;
        float acc[4] = {0.f, 0.f, 0.f, 0.f};
#pragma unroll
        for (int jc = 0; jc < 4; jc++) {
            short4v v = *(const short4v*)&Xpart[(long long)jc * NTOK * CDIM +
                                                (long long)i * CDIM + c];
#pragma unroll
            for (int k = 0; k < 4; k++) acc[k] += bf2f((u16)v[k]);
        }
        float invs = 1.f / sArr[h];
        float4 o;
        o.x = acc[0] * invs; o.y = acc[1] * invs; o.z = acc[2] * invs; o.w = acc[3] * invs;
        *(float4*)&out[(long long)i * 2048 + c] = o;
    }
    // ---- part B: output2 row i (2048 cols, 8 per thread)
    float invS[NH];
#pragma unroll
    for (int h = 0; h < NH; h++) invS[h] = 1.f / (8.f * sArr[h]);
    const int c0 = t * 8;
    float a[8] = {0.f, 0.f, 0.f, 0.f, 0.f, 0.f, 0.f, 0.f};
#pragma unroll
    for (int h = 0; h < NH; h++) {
        short8 p = *(const short8*)&P[((long long)h * NTOK + i) * NTOK + c0];
#pragma unroll
        for (int k = 0; k < 8; k++) a[k] += bf2f((u16)p[k]) * invS[h];
    }
    uint2 mv = *(const uint2*)(mask + (long long)i * NTOK + c0);  // 8B-aligned
    unsigned char mk[8];
#pragma unroll
    for (int k = 0; k < 4; k++) {
        mk[k] = (unsigned char)((mv.x >> (8 * k)) & 0xffu);
        mk[k + 4] = (unsigned char)((mv.y >> (8 * k)) & 0xffu);
    }
    float e[8];
    float part = 0.f;
#pragma unroll
    for (int k = 0; k < 8; k++) {
        e[k] = __expf(a[k]);
        if (mk[k]) part += e[k];
    }
    // wave butterfly + cross-wave combine (single barrier)
    part += __shfl_xor(part, 1);
    part += __shfl_xor(part, 2);
    part += __shfl_xor(part, 4);
    part += __shfl_xor(part, 8);
    part += __shfl_xor(part, 16);
    part += __shfl_xor(part, 32);
    if (lane == 0) redw[w4] = part;
    __syncthreads();
    float tot = (redw[0] + redw[1]) + (redw[2] + redw[3]);
    float invT = 1.f / tot;
    float o[8];
#pragma unroll
    for (int k = 0; k < 8; k++) o[k] = mk[k] ? e[k] * invT : 0.f;
    float4 o0, o1;
    o0.x = o[0]; o0.y = o[1]; o0.z = o[2]; o0.w = o[3];
    o1.x = o[4]; o1.y = o[5]; o1.z = o[6]; o1.w = o[7];
    float* dst = out2 + (long long)i * NTOK + c0;
    *(float4*)dst = o0;
    *(float4*)(dst + 4) = o1;
}

// ---------------------------------------------------------------- launcher
extern "C" void kernel_launch(void* const* d_in, const int* in_sizes, int n_in,
                              void* d_out, int out_size, void* d_ws,
                              size_t ws_size, hipStream_t stream) {
    (void)in_sizes; (void)n_in; (void)out_size; (void)ws_size;
    const float* x = (const float*)d_in[0];
    const float* cls = (const float*)d_in[1];
    // d_in[2] = fg_score: unused by the reference
    const float* Wq = (const float*)d_in[3];
    float* out = (float*)d_out;
    char* ws = (char*)d_ws;

    // Region [0, 23068672): early buffers (Xb/Wb dead after k_qkvn) overlaid
    // with Xpart/Spart (written only by k_attn9 afterwards).
    u16* Xb = (u16*)(ws + 0);                      //  4 MB  [2048,1024]
    u16* Wb = (u16*)(ws + 4194304);                //  6 MB  [3072,1024]
    u16* Xpart = (u16*)(ws + 0);                   // 16 MB  [4][2048,1024] bf16 PV partials
    float* Spart = (float*)(ws + 16777216);        // 512 KB [8][8,2048] row-sum partials
    u16* Qn = (u16*)(ws + 23068672);               //  4 MB
    u16* Kn = (u16*)(ws + 27262976);               //  4 MB
    u16* Vn = (u16*)(ws + 31457280);               //  4 MB
    u16* Vt = (u16*)(ws + 35651584);               //  4 MB  [1024,2048]
    unsigned char* mask = (unsigned char*)(ws + 39845888);  // 4 MB [2048,2048]
    u16* P = (u16*)(ws + 44040192);                // 67 MB [8,2048,2048]

    // 1. cast x and W to bf16
    k_cast<<<1024, 256, 0, stream>>>(x, Wq, Xb, Wb);

    // 2. fused QKV GEMM + norm + x_ori + Vt (R13-proven 384-block version)
    k_qkvn<<<dim3(24, 16), 256, 0, stream>>>(Xb, Wb, Qn, Kn, Vn, Vt, out);

    // 3. sim mask = (Vn @ Vn^T / 8 > 0.75) -> u8, full grid 128x64 tiles
    k_gemm_mask<<<dim3(32, 16), 256, 0, stream>>>(
        Vn, Vn, mask, CDIM, CDIM, CDIM, NTOK, 0.125f);

    // 4. fused logits+exp -> P, partial row sums, partial PV -> Xpart
    k_attn9<<<dim3(16, 4, NH), 256, 0, stream>>>(Qn, Kn, Vt, cls, P, Spart, Xpart);

    // 5. merged epilogue: x and output2
    k_epi<<<NTOK, 256, 0, stream>>>(Xpart, Spart, P, mask, out,
                                    out + (long long)NTOK * 2048);
}